// Round 2
// baseline (230.781 us; speedup 1.0000x reference)
//
#include <hip/hip_runtime.h>
#include <hip/hip_bf16.h>
#include <math.h>

#define B_  32
#define T_  128
#define NF_ 20
#define D_  512
#define S_  5
#define L_  96
#define EPS_ 1e-8f
#define NSEG (B_ * L_)                       // 3072
#define NPOS (NF_ - 1)                       // 19
#define NELEM (NF_ * D_)                     // 10240 floats = 40 KB
#define GLD 33                               // Gram leading dim (fp32), breaks bank stride
#define SPB 4                                // segments per block = 1 per wave
#define NBLK (NSEG / SPB)                    // 768 blocks, = 3 blocks/CU exactly

typedef short short8 __attribute__((ext_vector_type(8)));
typedef float f32x4  __attribute__((ext_vector_type(4)));

// packed f32x2 -> bf16x2 (RNE); union cast because __hip_bfloat162 is not
// trivially copyable on this ROCm. Compiler emits the packed cvt path.
__device__ __forceinline__ unsigned int pkbf16(float lo, float hi) {
  union { __hip_bfloat162 h; unsigned int u; } r;
  r.h = __float22bfloat162_rn(make_float2(lo, hi));
  return r.u;
}

__device__ __forceinline__ short8 cvt8(const float4 a, const float4 b) {
  union { short8 v; unsigned int u[4]; } r;
  r.u[0] = pkbf16(a.x, a.y);
  r.u[1] = pkbf16(a.z, a.w);
  r.u[2] = pkbf16(b.x, b.y);
  r.u[3] = pkbf16(b.z, b.w);
  return r.v;
}

// One wave == one segment. Fragments are loaded straight from global memory in
// MFMA A/B layout (lane r=lane&15 holds row r, k=(lane>>4)*8+j -> 8 consecutive
// floats = 2x global_load_dwordx4, all 16 K-steps fold into offset immediates).
// No LDS staging, no __syncthreads, all 4 waves issue MFMA concurrently.
__global__ __launch_bounds__(256) void phoneme_ssl_seg_kernel(
    const float* __restrict__ out,
    const int* __restrict__ batch_idx,
    const int* __restrict__ time_idx,
    const int* __restrict__ neg_idx,
    float* __restrict__ partials) {

  __shared__ float G[SPB * 32 * GLD];        // per-wave private 32x32 Gram, 16.9 KB total

  const int lane = threadIdx.x & 63;
  const int w    = threadIdx.x >> 6;
  const int n    = blockIdx.x * SPB + w;
  const int b = batch_idx[n];
  const int t = time_idx[n];
  const float* __restrict__ src = out + (size_t)(b * T_ + t) * NELEM;

  const int r = lane & 15;
  const int q = lane >> 4;                   // k-quad: k = q*8 + j
  const int row1 = (16 + r > 19) ? 19 : 16 + r;   // clamp; tile rows >=20 unused,
                                                  // dup lanes coalesce to same line
  const float4* __restrict__ p0 = (const float4*)src + (r    * 128 + q * 2);
  const float4* __restrict__ p1 = (const float4*)src + (row1 * 128 + q * 2);

  // prefetch negative indices (tiny table, L2-resident) to hide latency in the tail
  int fneg[S_];
  if (lane < NPOS) {
#pragma unroll
    for (int j = 0; j < S_; ++j) fneg[j] = neg_idx[lane * S_ + j];
  }

  // ---- Gram via MFMA: G = V * V^T, 2x2 tiles of 16x16x32 (layout verified) ----
  f32x4 c00 = {0.f, 0.f, 0.f, 0.f}, c01 = c00, c10 = c00, c11 = c00;
#pragma unroll
  for (int ks = 0; ks < D_ / 32; ++ks) {     // 16 K-steps of 32
    const float4 x0 = p0[8 * ks];            // global_load_dwordx4, offset imm
    const float4 x1 = p0[8 * ks + 1];
    const float4 y0 = p1[8 * ks];
    const float4 y1 = p1[8 * ks + 1];
    const short8 a0 = cvt8(x0, x1);
    const short8 a1 = cvt8(y0, y1);
    // B fragment == A fragment for Gram (B[k][n] = V[n][k])
    c00 = __builtin_amdgcn_mfma_f32_16x16x32_bf16(a0, a0, c00, 0, 0, 0);
    c01 = __builtin_amdgcn_mfma_f32_16x16x32_bf16(a0, a1, c01, 0, 0, 0);
    c10 = __builtin_amdgcn_mfma_f32_16x16x32_bf16(a1, a0, c10, 0, 0, 0);
    c11 = __builtin_amdgcn_mfma_f32_16x16x32_bf16(a1, a1, c11, 0, 0, 0);
  }

  // C/D layout (verified): col = lane&15, row = (lane>>4)*4 + reg
  float* __restrict__ Gw = G + w * (32 * GLD);
#pragma unroll
  for (int reg = 0; reg < 4; ++reg) {
    const int rr = q * 4 + reg;
    Gw[rr        * GLD + r]      = c00[reg];
    Gw[rr        * GLD + 16 + r] = c01[reg];
    Gw[(16 + rr) * GLD + r]      = c10[reg];
    Gw[(16 + rr) * GLD + 16 + r] = c11[reg];
  }
  __threadfence_block();                     // order ds_write -> ds_read within wave

  // ---- softmax rows from Gram, lanes 0..18 of each wave ----
  float local = 0.f;
  if (lane < NPOS) {
    const int i = lane;
    const float na = sqrtf(Gw[i * GLD + i]);
    float sims[1 + S_];
    {
      const float nb = sqrtf(Gw[(i + 1) * GLD + (i + 1)]);
      sims[0] = Gw[i * GLD + (i + 1)] / fmaxf(na * nb, EPS_);
    }
#pragma unroll
    for (int j = 0; j < S_; ++j) {
      const int f = fneg[j];
      const float nb = sqrtf(Gw[f * GLD + f]);
      sims[1 + j] = Gw[i * GLD + f] / fmaxf(na * nb, EPS_);
    }
    float m = sims[0];
#pragma unroll
    for (int j = 1; j < 1 + S_; ++j) m = fmaxf(m, sims[j]);
    float se = 0.f;
#pragma unroll
    for (int j = 0; j < 1 + S_; ++j) se += expf(sims[j] - m);
    const float lse = m + logf(se);
    local = -(sims[0] - lse);                // -log_softmax[...,0]
  }

  // ---- per-wave reduce + one store per wave ----
#pragma unroll
  for (int off = 32; off >= 1; off >>= 1)
    local += __shfl_xor(local, off, 64);
  if (lane == 0) partials[n] = local;
}

__global__ __launch_bounds__(256) void phoneme_ssl_reduce_kernel(
    const float* __restrict__ partials, float* __restrict__ loss_out) {
  float acc = 0.f;
  for (int i = threadIdx.x; i < NSEG; i += 256) acc += partials[i];
#pragma unroll
  for (int off = 32; off >= 1; off >>= 1)
    acc += __shfl_xor(acc, off, 64);
  __shared__ float ws[4];
  if ((threadIdx.x & 63) == 0) ws[threadIdx.x >> 6] = acc;
  __syncthreads();
  if (threadIdx.x == 0)
    loss_out[0] = (ws[0] + ws[1] + ws[2] + ws[3]) * (1.0f / (float)(NSEG * NPOS));
}

extern "C" void kernel_launch(void* const* d_in, const int* in_sizes, int n_in,
                              void* d_out, int out_size, void* d_ws, size_t ws_size,
                              hipStream_t stream) {
  const float* out_t    = (const float*)d_in[0];
  const int* batch_idx  = (const int*)d_in[1];
  const int* time_idx   = (const int*)d_in[2];
  const int* neg_idx    = (const int*)d_in[3];
  float* loss_out       = (float*)d_out;
  float* partials       = (float*)d_ws;      // NSEG floats, fully overwritten each call

  phoneme_ssl_seg_kernel<<<NBLK, 256, 0, stream>>>(
      out_t, batch_idx, time_idx, neg_idx, partials);
  phoneme_ssl_reduce_kernel<<<1, 256, 0, stream>>>(partials, loss_out);
}